// Round 2
// baseline (28.742 us; speedup 1.0000x reference)
//
#include <hip/hip_runtime.h>

// Reference (traced through jax.lax.conv_transpose with transpose_kernel=True, IOHW):
//   out[n,co] = (1/1225) * sum_ci Sx[n,ci] * Sw[co,ci] + bias[co]
//   Sx[n,ci]  = sum over 32x32 spatial of x[n,ci]
//   Sw[d0,d1] = sum over 4x4 taps of weight[d0,d1]   (weight dim0 indexed by co!)

// ---- Kernel 1: Sx. One block per (n,c) row of 1024 contiguous floats. ----
__global__ __launch_bounds__(256) void k_reduce_x(const float* __restrict__ x,
                                                  float* __restrict__ sx) {
    const int row = blockIdx.x;  // n*256 + c, 16384 rows
    const float4 v = reinterpret_cast<const float4*>(x + (size_t)row * 1024)[threadIdx.x];
    float s = v.x + v.y + v.z + v.w;
    #pragma unroll
    for (int o = 32; o >= 1; o >>= 1) s += __shfl_down(s, o, 64);
    __shared__ float ws[4];
    const int lane = threadIdx.x & 63;
    const int wid  = threadIdx.x >> 6;
    if (lane == 0) ws[wid] = s;
    __syncthreads();
    if (threadIdx.x == 0) sx[row] = ws[0] + ws[1] + ws[2] + ws[3];
}

// ---- Kernel 2: tap-sum of weight, stored TRANSPOSED. ----
// Block d0, thread d1: sum w[d0,d1,:,:] (16 contiguous floats), store at [d1,d0].
__global__ __launch_bounds__(256) void k_reduce_w(const float* __restrict__ w,
                                                  float* __restrict__ swt) {
    const int d0 = blockIdx.x;
    const int d1 = threadIdx.x;
    const float4* p = reinterpret_cast<const float4*>(w + ((size_t)d0 * 256 + d1) * 16);
    float s = 0.f;
    #pragma unroll
    for (int k = 0; k < 4; ++k) {
        const float4 v = p[k];
        s += v.x + v.y + v.z + v.w;
    }
    swt[(size_t)d1 * 256 + d0] = s;  // swt[ci*256+co] = tapsum(w[co,ci])
}

// ---- Kernel 3: out[n,co] = (1/1225)*sum_ci Sx[n,ci]*swt[ci,co] + bias[co] ----
__global__ __launch_bounds__(256) void k_gemm(const float* __restrict__ sx,
                                              const float* __restrict__ swt,
                                              const float* __restrict__ bias,
                                              float* __restrict__ out) {
    const int n  = blockIdx.x;   // 64
    const int co = threadIdx.x;  // 256
    __shared__ float sxr[256];
    sxr[co] = sx[n * 256 + co];
    __syncthreads();
    float acc = 0.f;
    #pragma unroll 8
    for (int ci = 0; ci < 256; ++ci) acc += sxr[ci] * swt[ci * 256 + co];
    out[n * 256 + co] = acc * (1.0f / 1225.0f) + bias[co];
}

extern "C" void kernel_launch(void* const* d_in, const int* in_sizes, int n_in,
                              void* d_out, int out_size, void* d_ws, size_t ws_size,
                              hipStream_t stream) {
    const float* x    = (const float*)d_in[0];  // [64,256,32,32]
    const float* w    = (const float*)d_in[1];  // [256,256,4,4]
    const float* bias = (const float*)d_in[2];  // [256]
    float* out = (float*)d_out;                 // [64,256,1,1] fp32

    float* sx  = (float*)d_ws;                  // 64*256 floats = 64 KB
    float* swt = sx + 64 * 256;                 // 256*256 floats = 256 KB

    k_reduce_x<<<64 * 256, 256, 0, stream>>>(x, sx);
    k_reduce_w<<<256, 256, 0, stream>>>(w, swt);
    k_gemm<<<64, 256, 0, stream>>>(sx, swt, bias, out);
}

// Round 3
// 26.973 us; speedup vs baseline: 1.0656x; 1.0656x over previous
//
#include <hip/hip_runtime.h>

// out[n,co] = (1/1225) * sum_ci Sx[n,ci] * Sw[co,ci] + bias[co]
//   Sx[n,ci]  = sum over 32x32 spatial of x[n,ci]       (verified exact, absmax 0.0)
//   Sw[d0,d1] = sum over 4x4 taps of weight[d0,d1], stored transposed in ws.

#define XBLOCKS 4096   // 16384 rows / 4 rows per block

// ---- Kernel 1 (fused): blocks [0,4096) reduce x (4 rows each);
//      blocks [4096,4352) reduce w (one d0 row each, stored transposed). ----
__global__ __launch_bounds__(256) void k_reduce(const float* __restrict__ x,
                                                const float* __restrict__ w,
                                                float* __restrict__ sx,
                                                float* __restrict__ swt) {
    const int b = blockIdx.x;
    if (b < XBLOCKS) {
        const int row0 = b * 4;  // n*256+c base
        const float4* p = reinterpret_cast<const float4*>(x + (size_t)row0 * 1024);
        // 4 independent rows: 4 float4 loads in flight per thread
        float s0, s1, s2, s3;
        {
            const float4 v0 = p[threadIdx.x];
            const float4 v1 = p[256 + threadIdx.x];
            const float4 v2 = p[512 + threadIdx.x];
            const float4 v3 = p[768 + threadIdx.x];
            s0 = v0.x + v0.y + v0.z + v0.w;
            s1 = v1.x + v1.y + v1.z + v1.w;
            s2 = v2.x + v2.y + v2.z + v2.w;
            s3 = v3.x + v3.y + v3.z + v3.w;
        }
        #pragma unroll
        for (int o = 32; o >= 1; o >>= 1) {
            s0 += __shfl_xor(s0, o, 64);
            s1 += __shfl_xor(s1, o, 64);
            s2 += __shfl_xor(s2, o, 64);
            s3 += __shfl_xor(s3, o, 64);
        }
        __shared__ float ws4[4][4];  // [wave][row]
        const int lane = threadIdx.x & 63;
        const int wid  = threadIdx.x >> 6;
        if (lane == 0) {
            ws4[wid][0] = s0; ws4[wid][1] = s1; ws4[wid][2] = s2; ws4[wid][3] = s3;
        }
        __syncthreads();
        if (threadIdx.x < 4) {
            sx[row0 + threadIdx.x] = ws4[0][threadIdx.x] + ws4[1][threadIdx.x] +
                                     ws4[2][threadIdx.x] + ws4[3][threadIdx.x];
        }
    } else {
        const int d0 = b - XBLOCKS;   // weight dim0 (= co)
        const int d1 = threadIdx.x;   // weight dim1 (= ci)
        const float4* p = reinterpret_cast<const float4*>(w + ((size_t)d0 * 256 + d1) * 16);
        float s = 0.f;
        #pragma unroll
        for (int k = 0; k < 4; ++k) {
            const float4 v = p[k];
            s += v.x + v.y + v.z + v.w;
        }
        swt[(size_t)d1 * 256 + d0] = s;  // swt[ci*256+co] = tapsum(w[co,ci])
    }
}

// ---- Kernel 2: out[n,co] = (1/1225)*sum_ci Sx[n,ci]*swt[ci,co] + bias[co] ----
__global__ __launch_bounds__(256) void k_gemm(const float* __restrict__ sx,
                                              const float* __restrict__ swt,
                                              const float* __restrict__ bias,
                                              float* __restrict__ out) {
    const int n  = blockIdx.x;   // 64
    const int co = threadIdx.x;  // 256
    __shared__ float sxr[256];
    sxr[co] = sx[n * 256 + co];
    __syncthreads();
    float acc = 0.f;
    #pragma unroll 8
    for (int ci = 0; ci < 256; ++ci) acc += sxr[ci] * swt[ci * 256 + co];
    out[n * 256 + co] = acc * (1.0f / 1225.0f) + bias[co];
}

extern "C" void kernel_launch(void* const* d_in, const int* in_sizes, int n_in,
                              void* d_out, int out_size, void* d_ws, size_t ws_size,
                              hipStream_t stream) {
    const float* x    = (const float*)d_in[0];  // [64,256,32,32]
    const float* w    = (const float*)d_in[1];  // [256,256,4,4]
    const float* bias = (const float*)d_in[2];  // [256]
    float* out = (float*)d_out;                 // [64,256,1,1] fp32

    float* sx  = (float*)d_ws;                  // 64*256 floats
    float* swt = sx + 64 * 256;                 // 256*256 floats

    k_reduce<<<XBLOCKS + 256, 256, 0, stream>>>(x, w, sx, swt);
    k_gemm<<<64, 256, 0, stream>>>(sx, swt, bias, out);
}